// Round 9
// baseline (2304.607 us; speedup 1.0000x reference)
//
#include <hip/hip_runtime.h>

// Stacked LSTM (4 layers, units 100/80/50/30) + dense head, fp32, B=T=512.
//
// R8 findings (R0-R7 synthesis): the register allocator refuses to keep
// >~100 arch VGPRs of long-lived data; bigger weight arrays are spilled to
// AGPRs, and gfx950 VALU cannot read AGPRs as operands (R6 assembler error)
// -> one v_accvgpr_read per weight use = the measured ~700 cyc/step VALU
// inflation. PIN / launch_bounds / waves_per_eu / LDS-pad all failed to
// change the allocation.
//
// R9: stop fighting the RA. Hybrid weight placement:
//   - L0/L1: gates (f,i) weights in LDS, packed in EXACT per-(q,tid) read
//     order wl[q][tid][4] -> each wave ds_read_b128 covers a sequential
//     1KB: perfectly coalesced, zero bank conflicts, 8 cyc/instr data
//     limit. Gates (g,o) in registers: 68/60 floats < the RA's ~100
//     budget -> genuinely resident, no accvgpr traffic.
//   - L2/L3: full register weights (56/24 floats, fit budget).
//   Structure otherwise as R3/R4 (passed, absmax 3.7e-8): s-major GEMV
//   with broadcast act reads, packed-float4 z partials, 2 barriers/step,
//   ping-pong act buffers, x(t+1) prefetch. All fp32 (no fp32 MFMA).

#define T_SEQ 512
#define B_TOT 512

__device__ __forceinline__ float sigmoidf_(float x) {
    return 1.0f / (1.0f + __expf(-x));
}
__device__ __forceinline__ float tanh_fast(float x) {
    float e = __expf(2.0f * x);
    return 1.0f - 2.0f / (1.0f + e);   // saturates correctly at +-inf
}

// U: units, FI: input feats, S: k-slices, KH: k per slice (DIN4 = S*KH).
// LG: number of leading gates whose weights live in LDS (0 or 2).
template<int U, int FI, int S, int KH, int BLOCK, int LG, bool SEQ, bool FINAL>
__global__ __launch_bounds__(BLOCK, 2)
void lstm_layer(const float* __restrict__ X,    // [B][T][FI]
                const float* __restrict__ W,    // [DIN][4U] row-major
                const float* __restrict__ Bv,   // [4U] gate order f,i,g,o
                float* __restrict__ Hout,       // [B][T][U] if SEQ
                const float* __restrict__ Wd,   // [U] (FINAL)
                const float* __restrict__ bd,   // [1] (FINAL)
                float* __restrict__ OUT)        // [B] (FINAL)
{
    constexpr int DIN  = U + FI;
    constexpr int DIN4 = S * KH;
    static_assert(DIN4 >= DIN, "k-padding must cover DIN");
    static_assert((KH & 1) == 0, "KH even: one float4 = 2 k x 2 rows");
    constexpr int G  = 4 * U;
    constexpr int NT = S * U;
    constexpr int Q  = KH / 2;
    constexpr int RG = 4 - LG;           // register-resident gates
    static_assert(NT <= BLOCK, "GEMV threads must fit");
    static_assert(NT >= 2 * FI, "prefetch threads must be GEMV threads");
    static_assert(LG == 0 || LG == 2, "LG in {0,2}");
    constexpr int TOT = 2 * DIN4;

    __shared__ __align__(16) float  buf[2][TOT];       // {a_k,b_k} interleaved
    __shared__ __align__(16) float  zp[S * 2 * U * 4]; // [s][row][u][gate]
    __shared__ __align__(16) float4 wl[LG ? Q * NT : 1]; // [q][tid] gate f,i pairs

    const int tid = threadIdx.x;
    const int bb  = blockIdx.x * 2;      // two batch rows per block

    const int p = tid % U;               // unit
    const int s = tid / U;               // k-slice (GEMV threads: tid < NT)

    // ---- register weights: trailing RG gates (demand < RA's ~100 budget) --
    float w[RG][KH];
    if (tid < NT) {
        #pragma unroll
        for (int g = 0; g < RG; ++g) {
            #pragma unroll
            for (int kk = 0; kk < KH; ++kk) {
                const int k = s * KH + kk;
                w[g][kk] = (k < DIN) ? W[(size_t)k * G + (LG + g) * U + p] : 0.0f;
            }
        }
    }

    // ---- LDS weights: leading LG gates, packed in per-(q,tid) read order --
    if constexpr (LG == 2) {
        if (tid < NT) {
            #pragma unroll
            for (int q = 0; q < Q; ++q) {
                const int k0 = s * KH + 2 * q, k1 = k0 + 1;
                float4 wv;
                wv.x = (k0 < DIN) ? W[(size_t)k0 * G + 0 * U + p] : 0.0f;
                wv.y = (k1 < DIN) ? W[(size_t)k1 * G + 0 * U + p] : 0.0f;
                wv.z = (k0 < DIN) ? W[(size_t)k0 * G + 1 * U + p] : 0.0f;
                wv.w = (k1 < DIN) ? W[(size_t)k1 * G + 1 * U + p] : 0.0f;
                wl[q * NT + tid] = wv;
            }
        }
    }

    // ---- cell threads: tid < 2U -> (u = p, r = s in {0,1}) ----
    float cb4[4] = {0.f, 0.f, 0.f, 0.f};
    if (tid < 2 * U) {
        #pragma unroll
        for (int g = 0; g < 4; ++g) cb4[g] = Bv[g * U + p];
    }
    float hreg = 0.0f, creg = 0.0f;
    float wdreg = 0.0f;
    if constexpr (FINAL) { if (tid < 2 * U) wdreg = Wd[p]; }

    // ---- x-prefetch mapping (tid < 2*FI, all are GEMV threads) ----
    const int xr = (tid < FI) ? 0 : 1;
    const int xj = tid - xr * FI;
    const float* Xrow = X + (size_t)(bb + xr) * T_SEQ * FI + xj;
    const int xwi = 2 * (U + xj) + xr;

    // ---- init: zero both buffers (h=0 + k-pad), stage x(0) ----
    for (int i = tid; i < 2 * TOT; i += BLOCK) ((float*)buf)[i] = 0.0f;
    __syncthreads();
    if (tid < 2 * FI) buf[0][xwi] = Xrow[0];
    __syncthreads();

    const int rbase = s * Q;             // per-lane act f4 read base

    for (int t = 0; t < T_SEQ; ++t) {
        const int cur = t & 1, nxt = cur ^ 1;

        // prefetch x(t+1) global->reg; retires under the GEMV
        float xpre = 0.0f;
        const bool do_x = (tid < 2 * FI) && (t + 1 < T_SEQ);
        if (do_x) xpre = Xrow[(size_t)(t + 1) * FI];

        // ---- phase 1: GEMV partials ----
        if (tid < NT) {
            float a0 = 0.f, a1 = 0.f, a2 = 0.f, a3 = 0.f;   // row 0: f,i,g,o
            float b0 = 0.f, b1 = 0.f, b2 = 0.f, b3 = 0.f;   // row 1
            const float4* rb = (const float4*)buf[cur];
            #pragma unroll
            for (int q = 0; q < Q; ++q) {
                const float4 v = rb[rbase + q];  // {a(2q), b(2q), a(2q+1), b(2q+1)}
                if constexpr (LG == 2) {
                    const float4 wv = wl[q * NT + tid];  // {f2q,f2q1,i2q,i2q1}
                    a0 += wv.x * v.x; b0 += wv.x * v.y;
                    a0 += wv.y * v.z; b0 += wv.y * v.w;
                    a1 += wv.z * v.x; b1 += wv.z * v.y;
                    a1 += wv.w * v.z; b1 += wv.w * v.w;
                    a2 += w[0][2*q]   * v.x; b2 += w[0][2*q]   * v.y;
                    a2 += w[0][2*q+1] * v.z; b2 += w[0][2*q+1] * v.w;
                    a3 += w[1][2*q]   * v.x; b3 += w[1][2*q]   * v.y;
                    a3 += w[1][2*q+1] * v.z; b3 += w[1][2*q+1] * v.w;
                } else {
                    a0 += w[0][2*q] * v.x; b0 += w[0][2*q] * v.y;
                    a1 += w[1][2*q] * v.x; b1 += w[1][2*q] * v.y;
                    a2 += w[2][2*q] * v.x; b2 += w[2][2*q] * v.y;
                    a3 += w[3][2*q] * v.x; b3 += w[3][2*q] * v.y;
                    a0 += w[0][2*q+1] * v.z; b0 += w[0][2*q+1] * v.w;
                    a1 += w[1][2*q+1] * v.z; b1 += w[1][2*q+1] * v.w;
                    a2 += w[2][2*q+1] * v.z; b2 += w[2][2*q+1] * v.w;
                    a3 += w[3][2*q+1] * v.z; b3 += w[3][2*q+1] * v.w;
                }
            }
            float4* zq = (float4*)zp;
            zq[(s * 2 + 0) * U + p] = make_float4(a0, a1, a2, a3);
            zq[(s * 2 + 1) * U + p] = make_float4(b0, b1, b2, b3);
        }
        // stage x(t+1) reg->LDS (disjoint region from phase-2 h writes)
        if (do_x) buf[nxt][xwi] = xpre;
        __syncthreads();

        // ---- phase 2: reduce + cell update ----
        if (tid < 2 * U) {
            float z0 = cb4[0], z1 = cb4[1], z2 = cb4[2], z3 = cb4[3];
            const float4* zq = (const float4*)zp;
            #pragma unroll
            for (int ss = 0; ss < S; ++ss) {
                const float4 v = zq[(ss * 2 + s) * U + p];
                z0 += v.x; z1 += v.y; z2 += v.z; z3 += v.w;
            }
            const float F  = sigmoidf_(z0);
            const float I  = sigmoidf_(z1);
            const float Gv = tanh_fast(z2);
            const float O  = sigmoidf_(z3);
            creg = F * creg + I * Gv;
            hreg = O * tanh_fast(creg);
            buf[nxt][2 * p + s] = hreg;
            if constexpr (SEQ) {
                Hout[((size_t)(bb + s) * T_SEQ + t) * U + p] = hreg;
            }
        }
        __syncthreads();
    }

    if constexpr (FINAL) {
        if (tid < 2 * U) buf[0][2 * p + s] = hreg * wdreg;
        __syncthreads();
        if (tid < 2) {
            float acc = bd[0];
            for (int u = 0; u < U; ++u) acc += buf[0][2 * u + tid];
            OUT[bb + tid] = acc;
        }
    }
}

extern "C" void kernel_launch(void* const* d_in, const int* in_sizes, int n_in,
                              void* d_out, int out_size, void* d_ws, size_t ws_size,
                              hipStream_t stream)
{
    const float* x    = (const float*)d_in[0];
    const float* W0   = (const float*)d_in[1];
    const float* b0   = (const float*)d_in[2];
    const float* W1   = (const float*)d_in[3];
    const float* b1   = (const float*)d_in[4];
    const float* W2   = (const float*)d_in[5];
    const float* b2   = (const float*)d_in[6];
    const float* W3   = (const float*)d_in[7];
    const float* b3   = (const float*)d_in[8];
    const float* Wout = (const float*)d_in[9];
    const float* bout = (const float*)d_in[10];
    float* out = (float*)d_out;

    float* H0 = (float*)d_ws;                         // [512*512*100]
    float* H1 = H0 + (size_t)B_TOT * T_SEQ * 100;     // [512*512*80]
    float* H2 = (float*)d_ws;                         // reuses H0 slot

    const dim3 grid(B_TOT / 2);

    // <U, FI, S, KH, BLOCK, LG, SEQ, FINAL>
    // L0: LDS wl 17*500*16B = 136.0 KB + act/zp ~21.4 KB = 157.4 KB (<160).
    //     reg gates g,o: 68 floats -> under the RA's ~100-reg budget.
    // L1: wl 15*480*16B = 115.2 KB + ~21.1 KB = 136.3 KB; reg 60 floats.
    // L2/L3: all-register weights (56 / 24 floats).
    hipLaunchKernelGGL((lstm_layer<100,  64,  5, 34, 512, 2, true,  false>),
                       grid, dim3(512), 0, stream, x,  W0, b0, H0, nullptr, nullptr, nullptr);
    hipLaunchKernelGGL((lstm_layer< 80, 100,  6, 30, 512, 2, true,  false>),
                       grid, dim3(512), 0, stream, H0, W1, b1, H1, nullptr, nullptr, nullptr);
    hipLaunchKernelGGL((lstm_layer< 50,  80, 10, 14, 512, 0, true,  false>),
                       grid, dim3(512), 0, stream, H1, W2, b2, H2, nullptr, nullptr, nullptr);
    hipLaunchKernelGGL((lstm_layer< 30,  50, 16,  6, 512, 0, false, true >),
                       grid, dim3(512), 0, stream, H2, W3, b3, nullptr, Wout, bout, out);
}